// Round 5
// baseline (111.713 us; speedup 1.0000x reference)
//
#include <hip/hip_runtime.h>
#include <math.h>

// QuanvolutionPlus fused kernel, round 5.
// vs round 4 (~26us kernel inferred; bench 110.7; VALU-issue bound ~1140 instr/lane):
//  - BN folded into conv weights (w' = w*inv, acc init = addc): -8 ops/patch.
//  - conv + quantum rotation chain in PACKED f16 (v_pk_fma_f16), two patches per
//    pk op (lo=patch 2t, hi=patch 2t+1): conv 88->~45 instr per pair, quantum
//    chain+expvals 128->~48 per pair. sincos + encoding stay f32 scalar.
//  - v_perm_b32 repacks (z0A,z0B)/(z1A,z1B) -> per-patch (z0,z1) for the matvec.
//  - matvec (f16 fdot2 vs LDS lin_w), DPP reduce, softmax, store: unchanged.
//
// Index facts (verified r1-r2): cls flat n = c*196+p ; q flat n = 4p+k ;
// logits[o] = sum_n fused[n]*lin_w[o*784+n] + lin_b[o].

#define NW 4                 // waves per block; 2 samples per wave
#define SCLS_STRIDE 794      // f16 elems per sample; odd word count de-phases halves

typedef __fp16 h2 __attribute__((ext_vector_type(2)));
typedef __fp16 h4 __attribute__((ext_vector_type(4)));

#define FDOT2(a, b, c) __builtin_amdgcn_fdot2((a), (b), (c), false)
#define PK(a, b) __builtin_amdgcn_cvt_pkrtz((a), (b))

__device__ __forceinline__ unsigned h2u(h2 v) { return __builtin_bit_cast(unsigned, v); }
__device__ __forceinline__ h2 uh2(unsigned v) { return __builtin_bit_cast(h2, v); }

// 32-lane segmented sum; returns {sum lanes0-31, sum lanes32-63}
__device__ __forceinline__ float2 red32x2(float x) {
    int v;
    v = __builtin_amdgcn_update_dpp(0, __float_as_int(x), 0x111, 0xf, 0xf, true); x += __int_as_float(v);
    v = __builtin_amdgcn_update_dpp(0, __float_as_int(x), 0x112, 0xf, 0xf, true); x += __int_as_float(v);
    v = __builtin_amdgcn_update_dpp(0, __float_as_int(x), 0x114, 0xf, 0xf, true); x += __int_as_float(v);
    v = __builtin_amdgcn_update_dpp(0, __float_as_int(x), 0x118, 0xf, 0xf, true); x += __int_as_float(v);
    v = __builtin_amdgcn_update_dpp(0, __float_as_int(x), 0x142, 0xa, 0xf, true); x += __int_as_float(v);
    float2 r;
    r.x = __int_as_float(__builtin_amdgcn_readlane(__float_as_int(x), 31));
    r.y = __int_as_float(__builtin_amdgcn_readlane(__float_as_int(x), 63));
    return r;
}

// load the 3x3 stride-2 conv window for patch (i,j); a[0..8] row-major, halo-masked
__device__ __forceinline__ void load_patch(const float* __restrict__ xs,
                                           unsigned i, int j, float* a) {
    int omid = (int)(2 * i) * 28 + 2 * j;
    float2 Rm = *(const float2*)(xs + omid);                 // a11 a12
    float2 Rb = *(const float2*)(xs + omid + 28);            // a21 a22
    int ot = omid - 28; ot = (ot > 0) ? ot : 0;
    float2 Rt = *(const float2*)(xs + ot);                   // a01 a02
    int olt = omid - 30; olt = (olt > 0) ? olt : 0;
    float2 Lt = *(const float2*)(xs + olt);                  // .y = a00
    int olm = omid - 2; olm = (olm > 0) ? olm : 0;
    float2 Lm = *(const float2*)(xs + olm);                  // .y = a10
    float2 Lb = *(const float2*)(xs + olm + 28);             // .y = a20
    float mt = (i > 0) ? 1.f : 0.f;
    float ml = (j > 0) ? 1.f : 0.f;
    a[0] = Lt.y * (mt * ml); a[1] = Rt.x * mt; a[2] = Rt.y * mt;
    a[3] = Lm.y * ml;        a[4] = Rm.x;      a[5] = Rm.y;
    a[6] = Lb.y * ml;        a[7] = Rb.x;      a[8] = Rb.y;
}

__global__ __launch_bounds__(256, 4)
void quanv_fused(const float* __restrict__ x,
                 const float* __restrict__ conv_w,
                 const float* __restrict__ bn_gamma,
                 const float* __restrict__ bn_beta,
                 const float* __restrict__ bn_mean,
                 const float* __restrict__ bn_var,
                 const float* __restrict__ var_params,
                 const float* __restrict__ lin_w,
                 const float* __restrict__ lin_b,
                 float* __restrict__ out, int B)
{
    __shared__ __align__(16) __fp16 lwh[7840];                     // 15680 B
    __shared__ __align__(16) __fp16 sclsAll[NW * 2 * SCLS_STRIDE]; // 12704 B

    const int tid  = threadIdx.x;
    const int wave = tid >> 6;
    const int lane = tid & 63;
    const int half = lane >> 5;
    const int l32  = lane & 31;

    const int s  = blockIdx.x * (NW * 2) + wave * 2 + half;
    const int sc = (s < B) ? s : (B - 1);
    const float* xs = x + (size_t)sc * 784;
    __fp16* myscls = &sclsAll[(wave * 2 + half) * SCLS_STRIDE];

    // ---- stage lin_w -> LDS as f16 (whole block, once) ----
    {
        const float4* src = (const float4*)lin_w;
        #pragma unroll
        for (int t = 0; t < 8; ++t) {
            int i = tid + t * 256;
            if (i < 1960) {
                float4 v = src[i];
                h2 a = PK(v.x, v.y);
                h2 b = PK(v.z, v.w);
                h4 w4 = { a.x, a.y, b.x, b.y };
                *(h4*)&lwh[4 * i] = w4;
            }
        }
    }

    // ---- uniform params: BN-folded packed conv weights, packed rotations ----
    h2 w2[36];      // (w*inv, w*inv) per (c,k)
    h2 addc2[4];
    #pragma unroll
    for (int c = 0; c < 4; ++c) {
        float iv = bn_gamma[c] * rsqrtf(bn_var[c] + 1e-5f);
        float ac = bn_beta[c] - bn_mean[c] * iv;
        addc2[c] = PK(ac, ac);
        #pragma unroll
        for (int k = 0; k < 9; ++k) {
            float wf = conv_w[c * 9 + k] * iv;
            w2[c * 9 + k] = PK(wf, wf);
        }
    }
    h2 cv2[4], sv2[4];
    #pragma unroll
    for (int k = 0; k < 4; ++k) {
        float sk, ck;
        __sincosf(var_params[k] * 0.5f, &sk, &ck);
        cv2[k] = PK(ck, ck);
        sv2[k] = PK(sk, sk);
    }

    // ---- paired patch loop: patches (l32+64tt, l32+64tt+32) per iteration ----
    h2 qh[7][2];
    #pragma unroll
    for (int tt = 0; tt < 4; ++tt) {
        const int tA = 2 * tt, tB = 2 * tt + 1;
        int pA = l32 + 32 * tA, pB = l32 + 32 * tB;
        bool actA = (pA < 196), actB = (pB < 196);
        int pcA = actA ? pA : 195, pcB = actB ? pB : 195;
        unsigned iA = (unsigned)pcA / 14u; int jA = pcA - (int)iA * 14;
        unsigned iB = (unsigned)pcB / 14u; int jB = pcB - (int)iB * 14;

        float aA[9], aB[9];
        load_patch(xs, iA, jA, aA);
        load_patch(xs, iB, jB, aB);

        // ---- conv: 4ch x 9 pk_fma over the patch pair, BN folded ----
        h2 apk[9];
        #pragma unroll
        for (int k = 0; k < 9; ++k) apk[k] = PK(aA[k], aB[k]);
        const h2 hz = { (__fp16)0.f, (__fp16)0.f };
        #pragma unroll
        for (int c = 0; c < 4; ++c) {
            h2 acc = addc2[c];
            #pragma unroll
            for (int k = 0; k < 9; ++k) acc += w2[c * 9 + k] * apk[k];
            acc = __builtin_elementwise_max(acc, hz);
            if (actA) myscls[c * 196 + pcA] = acc.x;
            if (actB) myscls[c * 196 + pcB] = acc.y;
        }

        // ---- quantum: f32 sincos/encoding, packed-f16 rotation chain ----
        float haA = 0.5f * (aA[4] + aA[7]), hbA = 0.5f * (aA[5] + aA[8]);
        float haB = 0.5f * (aB[4] + aB[7]), hbB = 0.5f * (aB[5] + aB[8]);
        float c0A, s0A, c1A, s1A, c0B, s0B, c1B, s1B;
        __sincosf(haA, &s0A, &c0A); __sincosf(hbA, &s1A, &c1A);
        __sincosf(haB, &s0B, &c0B); __sincosf(hbB, &s1B, &c1B);
        // encoding + CNOT(0->1): m00=c0c1 m01=c0s1 m10=s0s1 m11=s0c1
        h2 M00 = PK(c0A * c1A, c0B * c1B);
        h2 M01 = PK(c0A * s1A, c0B * s1B);
        h2 M10 = PK(s0A * s1A, s0B * s1B);
        h2 M11 = PK(s0A * c1A, s0B * c1B);
        // RY(v0) wire0
        h2 T00 = cv2[0] * M00 - sv2[0] * M10;
        h2 T01 = cv2[0] * M01 - sv2[0] * M11;
        h2 T10 = sv2[0] * M00 + cv2[0] * M10;
        h2 T11 = sv2[0] * M01 + cv2[0] * M11;
        // RY(v1) wire1
        h2 U00 = cv2[1] * T00 - sv2[1] * T01;
        h2 U01 = sv2[1] * T00 + cv2[1] * T01;
        h2 U10 = cv2[1] * T10 - sv2[1] * T11;
        h2 U11 = sv2[1] * T10 + cv2[1] * T11;
        // CNOT(1->0): swap U01 <-> U11
        h2 V01 = U11, V11 = U01;
        // RY(v2) wire0
        h2 P00 = cv2[2] * U00 - sv2[2] * U10;
        h2 P01 = cv2[2] * V01 - sv2[2] * V11;
        h2 P10 = sv2[2] * U00 + cv2[2] * U10;
        h2 P11 = sv2[2] * V01 + cv2[2] * V11;
        // RY(v3) wire1
        h2 Q00 = cv2[3] * P00 - sv2[3] * P01;
        h2 Q01 = sv2[3] * P00 + cv2[3] * P01;
        h2 Q10 = cv2[3] * P10 - sv2[3] * P11;
        h2 Q11 = sv2[3] * P10 + cv2[3] * P11;
        // expvals (packed over the pair)
        h2 sq00 = Q00 * Q00, sq01 = Q01 * Q01, sq10 = Q10 * Q10, sq11 = Q11 * Q11;
        h2 z0 = (sq00 + sq01) - (sq10 + sq11);
        h2 z1 = (sq00 + sq10) - (sq01 + sq11);
        h2 x0 = Q00 * Q10 + Q01 * Q11; x0 = x0 + x0;
        h2 x1 = Q00 * Q01 + Q10 * Q11; x1 = x1 + x1;

        unsigned z0u = h2u(z0), z1u = h2u(z1), x0u = h2u(x0), x1u = h2u(x1);
        qh[tA][0] = uh2(__builtin_amdgcn_perm(z1u, z0u, 0x05040100));  // (z0A,z1A)
        qh[tA][1] = uh2(__builtin_amdgcn_perm(x1u, x0u, 0x05040100));  // (x0A,x1A)
        if (tB < 7) {
            qh[tB][0] = uh2(__builtin_amdgcn_perm(z1u, z0u, 0x07060302));  // (z0B,z1B)
            qh[tB][1] = uh2(__builtin_amdgcn_perm(x1u, x0u, 0x07060302));  // (x0B,x1B)
        }
    }

    __syncthreads();   // lin_w staging visible block-wide; orders scls too

    // ---- fused matvec in f16 against LDS lin_w ----
    float ps[10];
    #pragma unroll
    for (int o = 0; o < 10; ++o) ps[o] = 0.f;

    const h2 hz = { (__fp16)0.f, (__fp16)0.f };
    #pragma unroll
    for (int t = 0; t < 7; ++t) {
        int p = l32 + 32 * t;
        bool act = (p < 196);
        int pc = act ? p : 195;
        h2 c0 = *(const h2*)&myscls[4 * pc];
        h2 c1 = *(const h2*)&myscls[4 * pc + 2];
        h2 f0 = c0 + qh[t][0];
        h2 f1 = c1 + qh[t][1];
        f0 = act ? f0 : hz;
        f1 = act ? f1 : hz;
        const __fp16* wbase = &lwh[4 * pc];
        #pragma unroll
        for (int o = 0; o < 10; ++o) {
            h4 wv = *(const h4*)&wbase[o * 784];
            h2 wlo = __builtin_shufflevector(wv, wv, 0, 1);
            h2 whi = __builtin_shufflevector(wv, wv, 2, 3);
            ps[o] = FDOT2(f0, wlo, ps[o]);
            ps[o] = FDOT2(f1, whi, ps[o]);
        }
    }

    // ---- reduce both halves; softmax; store ----
    float lg[10];
    #pragma unroll
    for (int o = 0; o < 10; ++o) {
        float2 r = red32x2(ps[o]);
        lg[o] = (half ? r.y : r.x) + lin_b[o];
    }

    float mx = lg[0];
    #pragma unroll
    for (int o = 1; o < 10; ++o) mx = fmaxf(mx, lg[o]);
    float se = 0.f;
    #pragma unroll
    for (int o = 0; o < 10; ++o) se += __expf(lg[o] - mx);
    float ls = __logf(se);

    if (l32 < 10 && s < B) {
        float v = lg[0];
        #pragma unroll
        for (int o = 1; o < 10; ++o) v = (l32 == o) ? lg[o] : v;
        out[(size_t)s * 10 + l32] = v - mx - ls;
    }
}

extern "C" void kernel_launch(void* const* d_in, const int* in_sizes, int n_in,
                              void* d_out, int out_size, void* d_ws, size_t ws_size,
                              hipStream_t stream) {
    const float* x          = (const float*)d_in[0];
    const float* conv_w     = (const float*)d_in[1];
    const float* bn_gamma   = (const float*)d_in[2];
    const float* bn_beta    = (const float*)d_in[3];
    const float* bn_mean    = (const float*)d_in[4];
    const float* bn_var     = (const float*)d_in[5];
    const float* var_params = (const float*)d_in[6];
    const float* lin_w      = (const float*)d_in[7];
    const float* lin_b      = (const float*)d_in[8];
    float* out = (float*)d_out;

    const int B = in_sizes[0] / 784;
    const int blocks = (B + NW * 2 - 1) / (NW * 2);
    quanv_fused<<<blocks, 256, 0, stream>>>(x, conv_w, bn_gamma, bn_beta, bn_mean,
                                            bn_var, var_params, lin_w, lin_b, out, B);
}